// Round 3
// baseline (140.148 us; speedup 1.0000x reference)
//
#include <hip/hip_runtime.h>
#include <cmath>

#define DIM    64
#define MCODE  512
#define ROWS   131072
#define QELEMS 8388608   // 32*4096*64
#define BM     128       // rows per block
#define BCODE  128       // codes per chunk
#define NCHUNK 4
#define TPB    256

// async global->LDS, 16B per lane; LDS dest = wave-uniform base + lane*16
__device__ __forceinline__ void async16(void* l, const void* g) {
    __builtin_amdgcn_global_load_lds(
        (const __attribute__((address_space(1))) unsigned int*)g,
        (__attribute__((address_space(3))) unsigned int*)l, 16, 0, 0);
}

// ---------------- prep: c[m] = ||e_m||^2 (numpy pairwise order), zero accumulators
__global__ __launch_bounds__(512) void vq_prep(const float* __restrict__ E,
                                               float* __restrict__ cvec,
                                               unsigned int* __restrict__ counts,
                                               double* __restrict__ lsum) {
    const int m = threadIdx.x;            // 512 threads, 1 block
    counts[m] = 0u;
    if (m == 0) *lsum = 0.0;
    const float* e = E + (size_t)m * DIM;
    float r[8];
#pragma unroll
    for (int j = 0; j < 8; ++j) r[j] = e[j] * e[j];
#pragma unroll
    for (int i = 1; i < 8; ++i)
#pragma unroll
        for (int j = 0; j < 8; ++j) r[j] += e[8 * i + j] * e[8 * i + j];
    cvec[m] = ((r[0] + r[1]) + (r[2] + r[3])) + ((r[4] + r[5]) + (r[6] + r[7]));
}

// ---------------- main: register-tiled distance GEMM + argmin + outputs
// LDS layout: xs[row][col'] / es[code][col'] with rotate swizzle
//   col'(row, g) = (g + (row & 15)) & 15   (float4-granularity columns)
__global__ __launch_bounds__(TPB, 2) void vq_main(const float* __restrict__ X,
                                                  const float* __restrict__ E,
                                                  const float* __restrict__ cvec,
                                                  float* __restrict__ out,
                                                  unsigned int* __restrict__ counts,
                                                  double* __restrict__ lsum) {
    __shared__ __align__(16) float xs[BM * DIM];      // 32 KB
    __shared__ __align__(16) float es[BCODE * DIM];   // 32 KB
    __shared__ float nxs[BM];
    __shared__ float sc[BCODE];
    __shared__ int bidxs[BM];
    __shared__ unsigned int hist[MCODE];
    __shared__ double red[TPB / 64];

    const int tid = threadIdx.x;
    const int w  = tid >> 6;     // wave id
    const int rg = tid >> 4;     // 0..15 : thread rows  = rg + 16*xi
    const int cg = tid & 15;     // 0..15 : thread codes = cg + 16*ei

    for (int i = tid; i < MCODE; i += TPB) hist[i] = 0u;

    // ---- stage X block: linear LDS dest, swizzled global source
    const float* Xb = X + (size_t)blockIdx.x * BM * DIM;
#pragma unroll
    for (int i = 0; i < 8; ++i) {
        const int s = i * TPB + tid;                       // float4 slot
        const int row = s >> 4;
        const int gk = ((s & 15) - (row & 15)) & 15;       // source k-group
        async16(((float4*)xs) + i * TPB + w * 64,
                (const float4*)Xb + row * 16 + gk);
    }
    // ---- stage E chunk 0
#pragma unroll
    for (int i = 0; i < 8; ++i) {
        const int s = i * TPB + tid;
        const int code = s >> 4;
        const int gk = ((s & 15) - (code & 15)) & 15;
        async16(((float4*)es) + i * TPB + w * 64,
                (const float4*)E + code * 16 + gk);
    }
    if (tid < BCODE) sc[tid] = cvec[tid];
    __syncthreads();   // vmcnt(0) drain: xs, es ready

    // ---- ||x||^2 per row, numpy pairwise 8-acc order (k = 4g+c)
    if (tid < BM) {
        const int row = tid;
        const float4* xr = (const float4*)(xs + row * DIM);
        float r[8];
        {
            float4 v = xr[(0 + (row & 15)) & 15];
            r[0] = v.x * v.x; r[1] = v.y * v.y; r[2] = v.z * v.z; r[3] = v.w * v.w;
            v = xr[(1 + (row & 15)) & 15];
            r[4] = v.x * v.x; r[5] = v.y * v.y; r[6] = v.z * v.z; r[7] = v.w * v.w;
        }
#pragma unroll
        for (int g = 2; g < 16; ++g) {
            const float4 v = xr[(g + (row & 15)) & 15];
            const int b = (g & 1) * 4;
            r[b + 0] = fmaf(v.x, v.x, r[b + 0]);
            r[b + 1] = fmaf(v.y, v.y, r[b + 1]);
            r[b + 2] = fmaf(v.z, v.z, r[b + 2]);
            r[b + 3] = fmaf(v.w, v.w, r[b + 3]);
        }
        nxs[row] = ((r[0] + r[1]) + (r[2] + r[3])) + ((r[4] + r[5]) + (r[6] + r[7]));
    }
    __syncthreads();

    float nx[8];
#pragma unroll
    for (int xi = 0; xi < 8; ++xi) nx[xi] = nxs[rg + 16 * xi];

    float bd[8]; int bi[8];
#pragma unroll
    for (int xi = 0; xi < 8; ++xi) { bd[xi] = __builtin_inff(); bi[xi] = 0; }

    const float* xbase = xs + rg * DIM;
    const float* ebase = es + cg * DIM;

    for (int ch = 0; ch < NCHUNK; ++ch) {
        if (ch) {
            __syncthreads();   // everyone done reading es/sc of prev chunk
#pragma unroll
            for (int i = 0; i < 8; ++i) {
                const int s = i * TPB + tid;
                const int code = s >> 4;
                const int gk = ((s & 15) - (code & 15)) & 15;
                async16(((float4*)es) + i * TPB + w * 64,
                        (const float4*)E + (ch * BCODE + code) * 16 + gk);
            }
            if (tid < BCODE) sc[tid] = cvec[ch * BCODE + tid];
            __syncthreads();   // es ready
        }

        float acc[8][8];
#pragma unroll
        for (int xi = 0; xi < 8; ++xi)
#pragma unroll
            for (int ei = 0; ei < 8; ++ei) acc[xi][ei] = 0.f;

#pragma unroll 4
        for (int g = 0; g < 16; ++g) {
            const int xo = ((g + rg) & 15) << 2;   // float offset of swizzled col
            const int eo = ((g + cg) & 15) << 2;
            float4 xv[8], ev[8];
#pragma unroll
            for (int xi = 0; xi < 8; ++xi)
                xv[xi] = *(const float4*)(xbase + xi * 16 * DIM + xo);  // imm offs xi*4096
#pragma unroll
            for (int ei = 0; ei < 8; ++ei)
                ev[ei] = *(const float4*)(ebase + ei * 16 * DIM + eo);
#pragma unroll
            for (int xi = 0; xi < 8; ++xi)
#pragma unroll
                for (int ei = 0; ei < 8; ++ei) {   // k = 4g+c ascending (ref order)
                    acc[xi][ei] = fmaf(xv[xi].x, ev[ei].x, acc[xi][ei]);
                    acc[xi][ei] = fmaf(xv[xi].y, ev[ei].y, acc[xi][ei]);
                    acc[xi][ei] = fmaf(xv[xi].z, ev[ei].z, acc[xi][ei]);
                    acc[xi][ei] = fmaf(xv[xi].w, ev[ei].w, acc[xi][ei]);
                }
        }

        // ---- combine + per-thread argmin (codes ascend within thread; strict <)
#pragma unroll
        for (int ei = 0; ei < 8; ++ei) {
            const int cl = cg + 16 * ei;
            const float c = sc[cl];
            const int code = ch * BCODE + cl;
#pragma unroll
            for (int xi = 0; xi < 8; ++xi) {
                const float d2 = fmaf(-2.f, acc[xi][ei], nx[xi]) + c;  // ref rounding
                if (d2 < bd[xi]) { bd[xi] = d2; bi[xi] = code; }
            }
        }
    }

    // ---- argmin reduce across the 16 cg lanes (offs 1,2,4,8 stay in same rg group)
#pragma unroll
    for (int off = 1; off < 16; off <<= 1) {
#pragma unroll
        for (int xi = 0; xi < 8; ++xi) {
            const float od = __shfl_xor(bd[xi], off, 64);
            const int oi = __shfl_xor(bi[xi], off, 64);
            if (od < bd[xi] || (od == bd[xi] && oi < bi[xi])) { bd[xi] = od; bi[xi] = oi; }
        }
    }
    if (cg == 0) {
#pragma unroll
        for (int xi = 0; xi < 8; ++xi) {
            bidxs[rg + 16 * xi] = bi[xi];
            atomicAdd(&hist[bi[xi]], 1u);
        }
    }
    __syncthreads();

    // ---- epilogue: quantised_st + loss, coalesced float4 writes
    float* outb = out + (size_t)blockIdx.x * BM * DIM;
    float ls = 0.f;
#pragma unroll
    for (int i = 0; i < 8; ++i) {
        const int gi = i * TPB + tid;       // float4 index in block
        const int row = gi >> 4;
        const int colL = gi & 15;
        const int bq = bidxs[row];
        const float4 qv = ((const float4*)E)[bq * 16 + colL];
        const float4 xv = ((const float4*)(xs + row * DIM))[(colL + (row & 15)) & 15];
        float4 o;
        { const float t = qv.x - xv.x; o.x = xv.x + t; const float dd = xv.x - qv.x; ls = fmaf(dd, dd, ls); }
        { const float t = qv.y - xv.y; o.y = xv.y + t; const float dd = xv.y - qv.y; ls = fmaf(dd, dd, ls); }
        { const float t = qv.z - xv.z; o.z = xv.z + t; const float dd = xv.z - qv.z; ls = fmaf(dd, dd, ls); }
        { const float t = qv.w - xv.w; o.w = xv.w + t; const float dd = xv.w - qv.w; ls = fmaf(dd, dd, ls); }
        ((float4*)outb)[gi] = o;
    }

    // ---- block loss reduction -> one double atomic
#pragma unroll
    for (int off = 32; off > 0; off >>= 1) ls += __shfl_down(ls, off);
    const int lane = tid & 63, wid = tid >> 6;
    if (lane == 0) red[wid] = (double)ls;
    __syncthreads();
    if (tid == 0) {
        double s = 0.0;
#pragma unroll
        for (int wv = 0; wv < TPB / 64; ++wv) s += red[wv];
        atomicAdd(lsum, s);
    }
    for (int i = tid; i < MCODE; i += TPB) {
        const unsigned int v = hist[i];
        if (v) atomicAdd(&counts[i], v);
    }
}

// ---------------- finalize: losses + perplexity
__global__ __launch_bounds__(512) void vq_fin(const unsigned int* __restrict__ counts,
                                              const double* __restrict__ lsum,
                                              float* __restrict__ out3) {
    __shared__ double sred[8];
    const int t = threadIdx.x;
    const double avg = (double)counts[t] / (double)ROWS;
    double term = avg * log(avg + 1e-10);
#pragma unroll
    for (int off = 32; off > 0; off >>= 1) term += __shfl_down(term, off);
    const int lane = t & 63, wid = t >> 6;
    if (lane == 0) sred[wid] = term;
    __syncthreads();
    if (t == 0) {
        double s = 0.0;
#pragma unroll
        for (int w = 0; w < 8; ++w) s += sred[w];
        const float perp = (float)exp(-s);
        const float rl = (float)(*lsum / (double)QELEMS);
        out3[0] = 0.25f * rl;   // commitment_loss
        out3[1] = rl;           // codebook_loss
        out3[2] = perp;         // perplexity
    }
}

extern "C" void kernel_launch(void* const* d_in, const int* in_sizes, int n_in,
                              void* d_out, int out_size, void* d_ws, size_t ws_size,
                              hipStream_t stream) {
    const float* X = (const float*)d_in[0];       // [32,4096,64] fp32
    const float* E = (const float*)d_in[1];       // [512,64] fp32
    float* out = (float*)d_out;                   // 8388608 + 3 floats

    double* lsum = (double*)d_ws;
    unsigned int* counts = (unsigned int*)((char*)d_ws + 8);
    float* cvec = (float*)((char*)d_ws + 8 + MCODE * sizeof(unsigned int));

    vq_prep<<<1, MCODE, 0, stream>>>(E, cvec, counts, lsum);
    vq_main<<<ROWS / BM, TPB, 0, stream>>>(X, E, cvec, out, counts, lsum);
    vq_fin<<<1, MCODE, 0, stream>>>(counts, lsum, out + QELEMS);
}